// Round 3
// baseline (73719.080 us; speedup 1.0000x reference)
//
#include <hip/hip_runtime.h>
#include <cstdint>
#include <cstddef>

#define SEQ 16384
#define INF 512
#define HID 1024
#define OUTF 256

#define NWG 64   // workgroups in recurrence
#define RPW 16   // rows per WG = HID/NWG

// ---------------------------------------------------------------- helpers

__device__ __forceinline__ float tanh_fast(float x) {
  float ax = fabsf(x);
  float e  = __expf(-2.0f * ax);          // e^{-2|x|} in (0,1]
  float r  = (1.0f - e) / (1.0f + e);     // tanh(|x|), no overflow
  return copysignf(r, x);
}

// 4x16B LLC-coherent loads, single waitcnt (bypass non-coherent L2)
__device__ __forceinline__ void llc_load16(const uint4* p, uint4& a, uint4& b,
                                           uint4& c, uint4& d) {
  asm volatile(
      "global_load_dwordx4 %0, %4, off sc0 sc1\n\t"
      "global_load_dwordx4 %1, %4, off offset:16 sc0 sc1\n\t"
      "global_load_dwordx4 %2, %4, off offset:32 sc0 sc1\n\t"
      "global_load_dwordx4 %3, %4, off offset:48 sc0 sc1\n\t"
      "s_waitcnt vmcnt(0)"
      : "=v"(a), "=v"(b), "=v"(c), "=v"(d)
      : "v"(p) : "memory");
}

// 4x4B LLC-coherent stores (scalar inputs: 128-bit asm inputs don't compile)
__device__ __forceinline__ void llc_store4(uint32_t* p, uint32_t a, uint32_t b,
                                           uint32_t c, uint32_t d) {
  asm volatile(
      "global_store_dword %0, %1, off sc0 sc1\n\t"
      "global_store_dword %0, %2, off offset:4 sc0 sc1\n\t"
      "global_store_dword %0, %3, off offset:8 sc0 sc1\n\t"
      "global_store_dword %0, %4, off offset:12 sc0 sc1"
      :: "v"(p), "v"(a), "v"(b), "v"(c), "v"(d) : "memory");
}

// ---------------------------------------------------------------- GEMM (NT)
// C[M,N] = A[M,K] * B[N,K]^T + (bias0+bias1+bias2)[N]
// 64x64 tile, 256 threads, 4x4 microtile, LDS stored k-major [k][m].
__global__ __launch_bounds__(256) void gemm_nt(
    const float* __restrict__ A, const float* __restrict__ B,
    const float* __restrict__ bias0, const float* __restrict__ bias1,
    const float* __restrict__ bias2,
    float* __restrict__ C, int M, int N, int K)
{
  __shared__ __align__(16) float As[64][68];
  __shared__ __align__(16) float Bs[64][68];
  const int tid = threadIdx.x;
  const int bm  = blockIdx.x * 64;
  const int bn  = blockIdx.y * 64;
  const int tm  = (tid >> 4) << 2;
  const int tn  = (tid & 15) << 2;

  float acc[4][4] = {};

  for (int k0 = 0; k0 < K; k0 += 64) {
    #pragma unroll
    for (int p = 0; p < 4; ++p) {
      int i  = tid + p * 256;
      int r  = i >> 4;
      int cc = (i & 15) << 2;
      float4 va = *(const float4*)(A + (size_t)(bm + r) * K + k0 + cc);
      As[cc+0][r] = va.x; As[cc+1][r] = va.y; As[cc+2][r] = va.z; As[cc+3][r] = va.w;
      float4 vb = *(const float4*)(B + (size_t)(bn + r) * K + k0 + cc);
      Bs[cc+0][r] = vb.x; Bs[cc+1][r] = vb.y; Bs[cc+2][r] = vb.z; Bs[cc+3][r] = vb.w;
    }
    __syncthreads();
    #pragma unroll
    for (int kk = 0; kk < 64; ++kk) {
      float4 a = *(const float4*)&As[kk][tm];
      float4 b = *(const float4*)&Bs[kk][tn];
      float av[4] = {a.x, a.y, a.z, a.w};
      float bv[4] = {b.x, b.y, b.z, b.w};
      #pragma unroll
      for (int i = 0; i < 4; ++i)
        #pragma unroll
        for (int j = 0; j < 4; ++j)
          acc[i][j] = fmaf(av[i], bv[j], acc[i][j]);
    }
    __syncthreads();
  }

  #pragma unroll
  for (int i = 0; i < 4; ++i) {
    #pragma unroll
    for (int j = 0; j < 4; ++j) {
      int col = bn + tn + j;
      float bs = 0.0f;
      if (bias0) bs += bias0[col];
      if (bias1) bs += bias1[col];
      if (bias2) bs += bias2[col];
      C[(size_t)(bm + tm + i) * N + col] = acc[i][j] + bs;
    }
  }
}

// ---------------------------------------------------------------- recurrence
// 64 WGs x 256 thr. WG b owns rows [16b,16b+16): wave wv owns 4 consecutive
// rows. Whh entirely in VGPRs (64 floats/thread; launch_bounds(256,1) so it
// does NOT spill). h broadcast via 2-slot global buffer; step tag in the
// mantissa LSB of every word (self-validating). Per-wave staging: no
// __syncthreads anywhere in the loop — waves run fully independently.
__global__ __launch_bounds__(256, 1) void rnn_scan(
    const float* __restrict__ Whh,   // (HID,HID) row-major
    float* __restrict__ buf,         // (SEQ,HID): xh on entry, h on exit
    uint32_t* __restrict__ hb)       // (2,HID) broadcast slots
{
  const int tid     = threadIdx.x;
  const int lane    = tid & 63;
  const int wv      = tid >> 6;            // wave 0..3
  const int seg     = lane >> 2;           // 0..15 -> 64-col segment
  const int rowbase = blockIdx.x * RPW + wv * 4;  // 4 consecutive rows / wave
  const int myrow   = rowbase + (lane & 3);

  // one-time: this thread's 64 weights (row myrow, cols seg*64..+63)
  float w[64];
  {
    const float* ws = Whh + (size_t)myrow * HID + seg * 64;
    #pragma unroll
    for (int j = 0; j < 64; j += 4) {
      float4 v = *(const float4*)(ws + j);
      w[j] = v.x; w[j+1] = v.y; w[j+2] = v.z; w[j+3] = v.w;
    }
  }

  // per-wave double-buffered swizzled h staging: addr = c + (c>>6)*4
  __shared__ __align__(16) float hl[4][2][1088];

  // step 0: h0 = tanh(xh0)  (initial hidden state is all-zero)
  {
    float xh0 = (lane < 4) ? buf[myrow] : 0.0f;
    float hn  = tanh_fast(xh0);
    float h1 = __shfl(hn, 1), h2 = __shfl(hn, 2), h3 = __shfl(hn, 3);
    if (lane == 0) {
      float4 o; o.x = hn; o.y = h1; o.z = h2; o.w = h3;
      *(float4*)(buf + rowbase) = o;
      llc_store4(hb + rowbase,
                 (__float_as_uint(hn) & ~1u),
                 (__float_as_uint(h1) & ~1u),
                 (__float_as_uint(h2) & ~1u),
                 (__float_as_uint(h3) & ~1u));   // slot 0, tag 0
    }
  }

  for (int t = 1; t < SEQ; ++t) {
    // prefetch own xh early — overlaps the poll
    float xh_p = (lane < 4) ? buf[(size_t)t * HID + myrow] : 0.0f;

    // poll h_{t-1}: slot (t-1)&1, tag ((t-1)>>1)&1 in every word's LSB.
    // lane stages cols [lane*16, lane*16+16).
    const uint32_t tag = ((t - 1) >> 1) & 1u;
    const uint4* src = (const uint4*)(hb + ((t - 1) & 1) * HID + lane * 16);
    uint4 va, vb, vc, vd;
    for (;;) {
      llc_load16(src, va, vb, vc, vd);
      uint32_t bad = (va.x ^ tag) | (va.y ^ tag) | (va.z ^ tag) | (va.w ^ tag)
                   | (vb.x ^ tag) | (vb.y ^ tag) | (vb.z ^ tag) | (vb.w ^ tag)
                   | (vc.x ^ tag) | (vc.y ^ tag) | (vc.z ^ tag) | (vc.w ^ tag)
                   | (vd.x ^ tag) | (vd.y ^ tag) | (vd.z ^ tag) | (vd.w ^ tag);
      if ((bad & 1u) == 0u) break;
    }
    {
      // 16 consecutive floats -> padded LDS (all in one 64-block: contiguous)
      float* dst = &hl[wv][t & 1][lane * 16 + ((lane >> 2) << 2)];
      *(uint4*)(dst + 0)  = va;
      *(uint4*)(dst + 4)  = vb;
      *(uint4*)(dst + 8)  = vc;
      *(uint4*)(dst + 12) = vd;
    }
    // no barrier: this wave staged everything it reads

    // 64 MACs: row myrow, cols [seg*64, seg*64+64)
    const float* hr = &hl[wv][t & 1][seg * 68];
    float a0 = 0, a1 = 0, a2 = 0, a3 = 0;
    #pragma unroll
    for (int j = 0; j < 64; j += 4) {
      float4 hv = *(const float4*)(hr + j);
      a0 = fmaf(w[j],   hv.x, a0);
      a1 = fmaf(w[j+1], hv.y, a1);
      a2 = fmaf(w[j+2], hv.z, a2);
      a3 = fmaf(w[j+3], hv.w, a3);
    }
    float acc = (a0 + a1) + (a2 + a3);
    // reduce across 16 segs (lane bits 2..5) — every lane gets its row sum
    acc += __shfl_xor(acc, 4);
    acc += __shfl_xor(acc, 8);
    acc += __shfl_xor(acc, 16);
    acc += __shfl_xor(acc, 32);

    float hn = tanh_fast(xh_p + acc);        // valid in lanes 0..3
    float h1 = __shfl(hn, 1), h2 = __shfl(hn, 2), h3 = __shfl(hn, 3);
    if (lane == 0) {
      float4 o; o.x = hn; o.y = h1; o.z = h2; o.w = h3;
      *(float4*)(buf + (size_t)t * HID + rowbase) = o;   // outs for fc GEMM
      const uint32_t tw = (t >> 1) & 1u;
      llc_store4(hb + (t & 1) * HID + rowbase,
                 (__float_as_uint(hn) & ~1u) | tw,
                 (__float_as_uint(h1) & ~1u) | tw,
                 (__float_as_uint(h2) & ~1u) | tw,
                 (__float_as_uint(h3) & ~1u) | tw);
    }
  }
}

// ---------------------------------------------------------------- softmax
// in-place over rows of 256 (one block per row)
__global__ __launch_bounds__(256) void softmax256(float* __restrict__ C) {
  const int tid  = threadIdx.x;
  const int lane = tid & 63;
  const int wid  = tid >> 6;
  float* p = C + (size_t)blockIdx.x * OUTF;
  float x = p[tid];

  float m = x;
  #pragma unroll
  for (int o = 32; o > 0; o >>= 1) m = fmaxf(m, __shfl_xor(m, o));
  __shared__ float rm[4], rs[4];
  if (lane == 0) rm[wid] = m;
  __syncthreads();
  m = fmaxf(fmaxf(rm[0], rm[1]), fmaxf(rm[2], rm[3]));

  float e = __expf(x - m);
  float s = e;
  #pragma unroll
  for (int o = 32; o > 0; o >>= 1) s += __shfl_xor(s, o);
  if (lane == 0) rs[wid] = s;
  __syncthreads();
  s = rs[0] + rs[1] + rs[2] + rs[3];

  p[tid] = e / s;
}

// ---------------------------------------------------------------- launch

extern "C" void kernel_launch(void* const* d_in, const int* in_sizes, int n_in,
                              void* d_out, int out_size, void* d_ws, size_t ws_size,
                              hipStream_t stream) {
  (void)in_sizes; (void)n_in; (void)out_size; (void)ws_size;

  const float* input = (const float*)d_in[0];
  // d_in[1] = hidden_state (all zeros by construction)
  const float* Wxh_w = (const float*)d_in[2];
  const float* Wxh_b = (const float*)d_in[3];
  const float* Whh_w = (const float*)d_in[4];
  const float* Whh_b = (const float*)d_in[5];
  const float* bh    = (const float*)d_in[6];
  const float* fc_w  = (const float*)d_in[7];
  const float* fc_b  = (const float*)d_in[8];
  float* out = (float*)d_out;

  float*    buf = (float*)d_ws;                                   // SEQ*HID f32
  uint32_t* hb  = (uint32_t*)((char*)d_ws + (size_t)SEQ * HID * sizeof(float)); // 2*HID

  // all tag bits -> 1 so un-produced slots never match tag 0 at t=1,2
  (void)hipMemsetAsync(hb, 0x01, 2 * HID * sizeof(uint32_t), stream);

  // xh = input @ Wxh^T + (Wxh_b + Whh_b + bh)
  gemm_nt<<<dim3(SEQ / 64, HID / 64), 256, 0, stream>>>(
      input, Wxh_w, Wxh_b, Whh_b, bh, buf, SEQ, HID, INF);

  // sequential scan: buf becomes outs (h_t rows)
  rnn_scan<<<NWG, 256, 0, stream>>>(Whh_w, buf, hb);

  // logits = outs @ fc_w^T + fc_b  (into d_out)
  gemm_nt<<<dim3(SEQ / 64, OUTF / 64), 256, 0, stream>>>(
      buf, fc_w, fc_b, nullptr, nullptr, out, SEQ, OUTF, HID);

  // softmax rows in place
  softmax256<<<SEQ, 256, 0, stream>>>(out);
}

// Round 6
// 23799.892 us; speedup vs baseline: 3.0975x; 3.0975x over previous
//
#include <hip/hip_runtime.h>
#include <cstdint>
#include <cstddef>

#define SEQ 16384
#define INF 512
#define HID 1024
#define OUTF 256

#define NWG 64   // workgroups in recurrence
#define RPW 16   // rows per WG = HID/NWG

// ---------------------------------------------------------------- helpers

__device__ __forceinline__ float tanh_fast(float x) {
  float ax = fabsf(x);
  float e  = __expf(-2.0f * ax);          // e^{-2|x|} in (0,1]
  float r  = (1.0f - e) / (1.0f + e);     // tanh(|x|), no overflow
  return copysignf(r, x);
}

// 16B LLC-coherent load (bypass non-coherent L2): one transaction per poll
__device__ __forceinline__ uint4 llc_load4(const uint4* p) {
  uint4 r;
  asm volatile("global_load_dwordx4 %0, %1, off sc0 sc1\n\t"
               "s_waitcnt vmcnt(0)"
               : "=v"(r) : "v"(p) : "memory");
  return r;
}

// 4B LLC-coherent store (write-through past non-coherent L2)
__device__ __forceinline__ void llc_store1(uint32_t* p, uint32_t v) {
  asm volatile("global_store_dword %0, %1, off sc0 sc1"
               :: "v"(p), "v"(v) : "memory");
}

// ---------------------------------------------------------------- GEMM (NT)
// C[M,N] = A[M,K] * B[N,K]^T + (bias0+bias1+bias2)[N]
// 64x64 tile, 256 threads, 4x4 microtile, LDS stored k-major [k][m].
__global__ __launch_bounds__(256) void gemm_nt(
    const float* __restrict__ A, const float* __restrict__ B,
    const float* __restrict__ bias0, const float* __restrict__ bias1,
    const float* __restrict__ bias2,
    float* __restrict__ C, int M, int N, int K)
{
  __shared__ __align__(16) float As[64][68];
  __shared__ __align__(16) float Bs[64][68];
  const int tid = threadIdx.x;
  const int bm  = blockIdx.x * 64;
  const int bn  = blockIdx.y * 64;
  const int tm  = (tid >> 4) << 2;
  const int tn  = (tid & 15) << 2;

  float acc[4][4] = {};

  for (int k0 = 0; k0 < K; k0 += 64) {
    #pragma unroll
    for (int p = 0; p < 4; ++p) {
      int i  = tid + p * 256;
      int r  = i >> 4;
      int cc = (i & 15) << 2;
      float4 va = *(const float4*)(A + (size_t)(bm + r) * K + k0 + cc);
      As[cc+0][r] = va.x; As[cc+1][r] = va.y; As[cc+2][r] = va.z; As[cc+3][r] = va.w;
      float4 vb = *(const float4*)(B + (size_t)(bn + r) * K + k0 + cc);
      Bs[cc+0][r] = vb.x; Bs[cc+1][r] = vb.y; Bs[cc+2][r] = vb.z; Bs[cc+3][r] = vb.w;
    }
    __syncthreads();
    #pragma unroll
    for (int kk = 0; kk < 64; ++kk) {
      float4 a = *(const float4*)&As[kk][tm];
      float4 b = *(const float4*)&Bs[kk][tn];
      float av[4] = {a.x, a.y, a.z, a.w};
      float bv[4] = {b.x, b.y, b.z, b.w};
      #pragma unroll
      for (int i = 0; i < 4; ++i)
        #pragma unroll
        for (int j = 0; j < 4; ++j)
          acc[i][j] = fmaf(av[i], bv[j], acc[i][j]);
    }
    __syncthreads();
  }

  #pragma unroll
  for (int i = 0; i < 4; ++i) {
    #pragma unroll
    for (int j = 0; j < 4; ++j) {
      int col = bn + tn + j;
      float bs = 0.0f;
      if (bias0) bs += bias0[col];
      if (bias1) bs += bias1[col];
      if (bias2) bs += bias2[col];
      C[(size_t)(bm + tm + i) * N + col] = acc[i][j] + bs;
    }
  }
}

// ---------------------------------------------------------------- recurrence
// Round-1 proven skeleton (per-thread global poll of own 16B -> swizzled LDS
// write -> __syncthreads -> compute), with ONE change: the 64 per-thread
// weights are pinned in VGPRs by an empty volatile asm per element after a
// normal vectorized load. This severs the value<->memory link so the
// compiler cannot rematerialize the weight loads inside the t-loop (round-1
// failure mode: VGPR=52, 516MB FETCH). Budget: __launch_bounds__(256,1)
// -> 512 VGPRs/wave; 64 pinned + ~40 others fits easily.
__global__ __launch_bounds__(256, 1) void rnn_scan(
    const float* __restrict__ Whh,   // (HID,HID) row-major
    float* __restrict__ buf,         // (SEQ,HID): xh on entry, h on exit
    uint32_t* __restrict__ hb)       // (2,HID) broadcast slots
{
  const int tid     = threadIdx.x;
  const int lane    = tid & 63;
  const int seg     = lane >> 2;           // 0..15 -> 64-col segment
  const int wv      = tid >> 6;
  const int rowbase = blockIdx.x * RPW + wv * 4;
  const int myrow   = rowbase + (lane & 3);

  // one-time: this thread's 64 weights (row myrow, cols seg*64..+63)
  float w[64];
  {
    const float* wsrc = Whh + (size_t)myrow * HID + seg * 64;
    #pragma unroll
    for (int j = 0; j < 64; j += 4) {
      float4 v = *(const float4*)(wsrc + j);
      w[j] = v.x; w[j+1] = v.y; w[j+2] = v.z; w[j+3] = v.w;
    }
    // pin: zero-instruction opaque copy — kills rematerialization
    #pragma unroll
    for (int j = 0; j < 64; ++j) asm volatile("" : "+v"(w[j]));
  }

  // double-buffered swizzled h staging: word c -> addr c + 4*(c>>6)
  __shared__ __align__(16) float hl[2][1088];

  // step 0: h0 = tanh(xh0)  (initial hidden state is all-zero)
  {
    float xh0 = (lane < 4) ? buf[myrow] : 0.0f;
    float h0 = tanh_fast(xh0);
    if (lane < 4) {
      buf[myrow] = h0;
      llc_store1(hb + myrow, (__float_as_uint(h0) & ~1u));  // slot 0, tag 0
    }
  }

  for (int t = 1; t < SEQ; ++t) {
    // prefetch own xh early — overlaps the poll
    float xh_p = (lane < 4) ? buf[(size_t)t * HID + myrow] : 0.0f;

    // poll h_{t-1}: slot (t-1)&1, tag ((t-1)>>1)&1 in every word's LSB
    const uint32_t tag = ((t - 1) >> 1) & 1u;
    const uint4* src = (const uint4*)(hb + ((t - 1) & 1) * HID) + tid;
    uint4 v;
    for (;;) {
      v = llc_load4(src);
      if ((((v.x ^ tag) | (v.y ^ tag) | (v.z ^ tag) | (v.w ^ tag)) & 1u) == 0u)
        break;
    }
    {
      int c = tid * 4;   // words c..c+3 -> padded addr (0 conflicts, round 1)
      float4 f;
      f.x = __uint_as_float(v.x); f.y = __uint_as_float(v.y);
      f.z = __uint_as_float(v.z); f.w = __uint_as_float(v.w);
      *(float4*)&hl[t & 1][c + ((c >> 6) << 2)] = f;
    }
    __syncthreads();

    // 64 MACs: row myrow, cols [seg*64, seg*64+64)
    const float* hr = &hl[t & 1][seg * 68];
    float a0 = 0, a1 = 0, a2 = 0, a3 = 0;
    #pragma unroll
    for (int j = 0; j < 64; j += 4) {
      float4 hv = *(const float4*)(hr + j);
      a0 = fmaf(w[j],   hv.x, a0);
      a1 = fmaf(w[j+1], hv.y, a1);
      a2 = fmaf(w[j+2], hv.z, a2);
      a3 = fmaf(w[j+3], hv.w, a3);
    }
    float acc = (a0 + a1) + (a2 + a3);
    // reduce across 16 segs (lane bits 2..5) — every lane gets its row's sum
    acc += __shfl_xor(acc, 4);
    acc += __shfl_xor(acc, 8);
    acc += __shfl_xor(acc, 16);
    acc += __shfl_xor(acc, 32);

    float hn = tanh_fast(xh_p + acc);       // lane L holds row rowbase+(L&3)
    if (lane < 4) {
      buf[(size_t)t * HID + myrow] = hn;    // outs for fc GEMM
      llc_store1(hb + (t & 1) * HID + myrow,
                 (__float_as_uint(hn) & ~1u) | ((t >> 1) & 1u));
    }
  }
}

// ---------------------------------------------------------------- softmax
// in-place over rows of 256 (one block per row)
__global__ __launch_bounds__(256) void softmax256(float* __restrict__ C) {
  const int tid  = threadIdx.x;
  const int lane = tid & 63;
  const int wid  = tid >> 6;
  float* p = C + (size_t)blockIdx.x * OUTF;
  float x = p[tid];

  float m = x;
  #pragma unroll
  for (int o = 32; o > 0; o >>= 1) m = fmaxf(m, __shfl_xor(m, o));
  __shared__ float rm[4], rs[4];
  if (lane == 0) rm[wid] = m;
  __syncthreads();
  m = fmaxf(fmaxf(rm[0], rm[1]), fmaxf(rm[2], rm[3]));

  float e = __expf(x - m);
  float s = e;
  #pragma unroll
  for (int o = 32; o > 0; o >>= 1) s += __shfl_xor(s, o);
  if (lane == 0) rs[wid] = s;
  __syncthreads();
  s = rs[0] + rs[1] + rs[2] + rs[3];

  p[tid] = e / s;
}

// ---------------------------------------------------------------- launch

extern "C" void kernel_launch(void* const* d_in, const int* in_sizes, int n_in,
                              void* d_out, int out_size, void* d_ws, size_t ws_size,
                              hipStream_t stream) {
  (void)in_sizes; (void)n_in; (void)out_size; (void)ws_size;

  const float* input = (const float*)d_in[0];
  // d_in[1] = hidden_state (all zeros by construction)
  const float* Wxh_w = (const float*)d_in[2];
  const float* Wxh_b = (const float*)d_in[3];
  const float* Whh_w = (const float*)d_in[4];
  const float* Whh_b = (const float*)d_in[5];
  const float* bh    = (const float*)d_in[6];
  const float* fc_w  = (const float*)d_in[7];
  const float* fc_b  = (const float*)d_in[8];
  float* out = (float*)d_out;

  float*    buf = (float*)d_ws;                                   // SEQ*HID f32
  uint32_t* hb  = (uint32_t*)((char*)d_ws + (size_t)SEQ * HID * sizeof(float)); // 2*HID

  // all tag bits -> 1 so un-produced slots never match tag 0 at t=1,2
  (void)hipMemsetAsync(hb, 0x01, 2 * HID * sizeof(uint32_t), stream);

  // xh = input @ Wxh^T + (Wxh_b + Whh_b + bh)
  gemm_nt<<<dim3(SEQ / 64, HID / 64), 256, 0, stream>>>(
      input, Wxh_w, Wxh_b, Whh_b, bh, buf, SEQ, HID, INF);

  // sequential scan: buf becomes outs (h_t rows)
  rnn_scan<<<NWG, 256, 0, stream>>>(Whh_w, buf, hb);

  // logits = outs @ fc_w^T + fc_b  (into d_out)
  gemm_nt<<<dim3(SEQ / 64, OUTF / 64), 256, 0, stream>>>(
      buf, fc_w, fc_b, nullptr, nullptr, out, SEQ, OUTF, HID);

  // softmax rows in place
  softmax256<<<SEQ, 256, 0, stream>>>(out);
}